// Round 6
// baseline (444.939 us; speedup 1.0000x reference)
//
#include <hip/hip_runtime.h>
#include <hip/hip_bf16.h>

typedef __attribute__((ext_vector_type(4))) float f32x4;
typedef __attribute__((ext_vector_type(8))) short short8;
typedef unsigned short u16;

#define NROWS 8192
#define DM 1024
#define EPSF 1e-8f
#define NSPLIT 16     // column splits
#define SPLITW 512    // cols per split
#define NCT 4         // 128-col tiles per split

// async global->LDS, 16B per lane, wave-uniform LDS base (rule #21: linear dest,
// inverse-swizzled SOURCE, swizzle applied again on the ds_read side)
#define GLDS(gsrc, ldst) __builtin_amdgcn_global_load_lds(                 \
    (const __attribute__((address_space(1))) void*)(gsrc),                 \
    (__attribute__((address_space(3))) void*)(ldst), 16, 0, 0)

static __device__ __forceinline__ u16 f2bf(float x) {
  unsigned u = __float_as_uint(x);
  u += 0x7fffu + ((u >> 16) & 1u);   // RNE
  return (u16)(u >> 16);
}

// insert v into descending-sorted S[9]; all indices compile-time (stays in VGPRs)
static __device__ __forceinline__ void topk9_insert(float (&S)[9], float v) {
  if (v <= S[8]) return;
  S[8] = v;
#pragma unroll
  for (int q = 8; q > 0; --q) {
    float a = S[q - 1], b = S[q];
    S[q - 1] = fmaxf(a, b);
    S[q]     = fminf(a, b);
  }
}

// ---------------- kernel 1: row norm -> bf16 F, content logits ----------------
__global__ __launch_bounds__(256) void k_rowprep(
    const float* __restrict__ H, const float* __restrict__ Wc,
    const float* __restrict__ bc, u16* __restrict__ F, float* __restrict__ CL)
{
  const int r = blockIdx.x;
  const int t = threadIdx.x;
  const int lane = t & 63;
  const int w = t >> 6;

  const float4 h  = ((const float4*)(H  + (size_t)r * DM))[t];
  const float4 c0 = ((const float4*)(Wc + 0 * DM))[t];
  const float4 c1 = ((const float4*)(Wc + 1 * DM))[t];
  const float4 c2 = ((const float4*)(Wc + 2 * DM))[t];

  float ss = h.x*h.x + h.y*h.y + h.z*h.z + h.w*h.w;
  float d0 = h.x*c0.x + h.y*c0.y + h.z*c0.z + h.w*c0.w;
  float d1 = h.x*c1.x + h.y*c1.y + h.z*c1.z + h.w*c1.w;
  float d2 = h.x*c2.x + h.y*c2.y + h.z*c2.z + h.w*c2.w;

#pragma unroll
  for (int off = 32; off > 0; off >>= 1) {
    ss += __shfl_down(ss, off);
    d0 += __shfl_down(d0, off);
    d1 += __shfl_down(d1, off);
    d2 += __shfl_down(d2, off);
  }
  __shared__ float red[4][4];
  __shared__ float bcast;
  if (lane == 0) { red[w][0] = ss; red[w][1] = d0; red[w][2] = d1; red[w][3] = d2; }
  __syncthreads();
  if (t == 0) {
    float S  = red[0][0] + red[1][0] + red[2][0] + red[3][0];
    float D0 = red[0][1] + red[1][1] + red[2][1] + red[3][1];
    float D1 = red[0][2] + red[1][2] + red[2][2] + red[3][2];
    float D2 = red[0][3] + red[1][3] + red[2][3] + red[3][3];
    bcast = 1.0f / (sqrtf(S) + EPSF);
    CL[r*3+0] = D0 + bc[0];
    CL[r*3+1] = D1 + bc[1];
    CL[r*3+2] = D2 + bc[2];
  }
  __syncthreads();
  const float invn = bcast;
  ushort4 o;
  o.x = f2bf(h.x * invn); o.y = f2bf(h.y * invn);
  o.z = f2bf(h.z * invn); o.w = f2bf(h.w * invn);
  ((ushort4*)(F + (size_t)r * DM))[t] = o;
}

// ---------------- kernel 2: sim GEMM (bf16 MFMA) fused with top-9 ----------------
// grid (64 rowblocks of 128, 16 colsplits of 512). 256 threads = 4 waves, 3 blocks/CU.
// ONE top-9 list per thread: thread t owns global-local row (t>>7)*64 + ((t&127)>>1),
// scanning cols (t&1)*64..+64. Unified reg demand ~150 -> fits the (256,3) cap ~170.
__global__ __launch_bounds__(256, 3) void k_simtopk(
    const u16* __restrict__ F, float* __restrict__ partials)
{
  __shared__ char smem[32768];
  u16*   As = (u16*)smem;                  // [128][64] bf16 (swizzled chunks), 16 KiB
  u16*   Bs = (u16*)(smem + 16384);        // [128][64] bf16, 16 KiB
  float* Cs = (float*)smem;                // [64][128] f32 spill, additive-rotate slots (32 KiB)
  float* Ms = (float*)smem;                // [128][18] merge buffer (9 KiB)

  const int t    = threadIdx.x;
  const int lane = t & 63;
  const int w    = t >> 6;
  const int wr   = (w >> 1) * 64;
  const int wc   = (w & 1) * 64;
  const int R0    = blockIdx.x * 128;
  const int CBASE = blockIdx.y * SPLITW;
  const int wchunk = t & 192;              // wave-uniform chunk base within 256

  float S[9];
#pragma unroll
  for (int q = 0; q < 9; ++q) S[q] = -1e30f;

  const int myhalf = t >> 7;               // which 64-row half this thread scans
  const int u      = t & 127;
  const int srow   = u >> 1;               // row within half, 0..63
  const int cbase  = (u & 1) * 64;         // col range start

  for (int ct = 0; ct < NCT; ++ct) {
    const int C0 = CBASE + ct * 128;
    f32x4 acc[4][4];
#pragma unroll
    for (int i = 0; i < 4; ++i)
#pragma unroll
      for (int j = 0; j < 4; ++j)
        acc[i][j] = {0.f, 0.f, 0.f, 0.f};

    const char* Abase = (const char*)(F + (size_t)R0 * DM);
    const char* Bbase = (const char*)(F + (size_t)C0 * DM);
    for (int kk = 0; kk < 16; ++kk) {
      const int k0b = kk * 128;            // byte offset of k-chunk
#pragma unroll
      for (int it = 0; it < 4; ++it) {
        const int p = it * 256 + t;        // chunk id; recomputed (rematerializable)
        const int so = (p >> 3) * (DM * 2) + (((p & 7) ^ ((p >> 3) & 7)) * 16);
        GLDS(Abase + k0b + so, smem + (it * 256 + wchunk) * 16);
        GLDS(Bbase + k0b + so, smem + 16384 + (it * 256 + wchunk) * 16);
      }
      __syncthreads();   // compiler drains vmcnt(0) here
#pragma unroll
      for (int ks = 0; ks < 2; ++ks) {
        short8 b[4];
#pragma unroll
        for (int j = 0; j < 4; ++j) {
          const int row = wc + j * 16 + (lane & 15);
          const int c   = (ks * 4 + (lane >> 4)) ^ (lane & 7);
          b[j] = *(const short8*)(Bs + row * 64 + c * 8);
        }
#pragma unroll
        for (int i = 0; i < 4; ++i) {
          const int row = wr + i * 16 + (lane & 15);
          const int c   = (ks * 4 + (lane >> 4)) ^ (lane & 7);
          const short8 a = *(const short8*)(As + row * 64 + c * 8);
#pragma unroll
          for (int j = 0; j < 4; ++j)
            acc[i][j] = __builtin_amdgcn_mfma_f32_16x16x32_bf16(a, b[j], acc[i][j], 0, 0, 0);
        }
      }
      __syncthreads();
    }

    // spill + scan, one 64-row half at a time (C/D layout: col=lane&15, row=(lane>>4)*4+reg)
    // phys slot = ((col>>2) + row) & 31 : spill <=2-way, scan exactly 2-way (free)
#pragma unroll
    for (int half = 0; half < 2; ++half) {
      if ((w >> 1) == half) {
#pragma unroll
        for (int i = 0; i < 4; ++i)
#pragma unroll
          for (int j = 0; j < 4; ++j)
#pragma unroll
            for (int q = 0; q < 4; ++q) {
              const int rr = i * 16 + (lane >> 4) * 4 + q;
              const int cc = wc + j * 16 + (lane & 15);
              const int slot = ((cc >> 2) + rr) & 31;
              Cs[rr * 128 + (slot << 2) + (cc & 3)] = acc[i][j][q];
            }
      }
      __syncthreads();
      if (myhalf == half) {
        const float* crow = Cs + srow * 128;
#pragma unroll
        for (int g = 0; g < 16; ++g) {
          const int c0   = cbase + 4 * g;
          const int slot = ((c0 >> 2) + srow) & 31;
          const f32x4 v  = *(const f32x4*)(crow + (slot << 2));
          const float m  = fmaxf(fmaxf(v.x, v.y), fmaxf(v.z, v.w));
          if (m > S[8]) {
            topk9_insert(S, v.x); topk9_insert(S, v.y);
            topk9_insert(S, v.z); topk9_insert(S, v.w);
          }
        }
      }
      __syncthreads();
    }
  }

  // two threads per row -> merge pair lists -> top-9 partial for this colsplit
  {
    const int mrow = myhalf * 64 + srow;   // 0..127
#pragma unroll
    for (int q = 0; q < 9; ++q)
      Ms[mrow * 18 + (u & 1) * 9 + q] = S[q];
  }
  __syncthreads();
  if (t < 128) {
    const float* row = Ms + t * 18;
    float T[9];
#pragma unroll
    for (int q = 0; q < 9; ++q) T[q] = row[q];          // list 0, already descending
    for (int gq = 0; gq < 9; ++gq) {
      const float v = row[9 + gq];
      if (v <= T[8]) break;                             // list 1 descending
      topk9_insert(T, v);
    }
    float* dst = partials + (size_t)(R0 + t) * (NSPLIT * 9) + blockIdx.y * 9;
#pragma unroll
    for (int q = 0; q < 9; ++q) dst[q] = T[q];          // descending
  }
}

// ---------------- kernel 3: merge partials, features, MLP, mix, softmax ----------------
__global__ __launch_bounds__(256) void k_finalize(
    const float* __restrict__ partials, const float* __restrict__ CL,
    const float* __restrict__ W1, const float* __restrict__ b1,
    const float* __restrict__ W2, const float* __restrict__ b2,
    const float* __restrict__ alpha, float* __restrict__ out)
{
  const int n = blockIdx.x * 256 + threadIdx.x;
  if (n >= NROWS) return;
  const float* p = partials + (size_t)n * (NSPLIT * 9);
  float S[9];
#pragma unroll
  for (int q = 0; q < 9; ++q) S[q] = -1e30f;
  for (int grp = 0; grp < NSPLIT; ++grp) {
    for (int gq = 0; gq < 9; ++gq) {
      const float v = p[grp * 9 + gq];
      if (v <= S[8]) break;               // groups are descending
      topk9_insert(S, v);
    }
  }
  // S[0] is the self-similarity (max) -> dropped; knn sims are S[1..8]
  float sum = 0.f, sumsq = 0.f;
#pragma unroll
  for (int q = 1; q < 9; ++q) { sum += S[q]; sumsq += S[q] * S[q]; }
  const float mean_s  = sum * 0.125f;
  float var = (sumsq - 8.f * mean_s * mean_s) * (1.f / 7.f);  // ddof=1
  var = fmaxf(var, 0.f);
  const float tree    = sqrtf(var);
  const float density = 1.f - mean_s;
  const float outlier = (1.f - S[8]) / (density + EPSF);      // min sim = max dist

  float a0 = b2[0], a1 = b2[1], a2 = b2[2];
#pragma unroll
  for (int j = 0; j < 32; ++j) {
    float hj = W1[j*3+0]*tree + W1[j*3+1]*density + W1[j*3+2]*outlier + b1[j];
    hj = fmaxf(hj, 0.f);
    a0 += W2[j]      * hj;
    a1 += W2[32 + j] * hj;
    a2 += W2[64 + j] * hj;
  }
  const float mix = 1.f / (1.f + expf(-alpha[0]));
  const float im  = 1.f - mix;
  const float l0 = mix * CL[n*3+0] + im * a0;
  const float l1 = mix * CL[n*3+1] + im * a1;
  const float l2 = mix * CL[n*3+2] + im * a2;
  const float mx = fmaxf(l0, fmaxf(l1, l2));
  const float e0 = expf(l0 - mx), e1 = expf(l1 - mx), e2 = expf(l2 - mx);
  const float inv = 1.f / (e0 + e1 + e2);
  out[n*3+0] = e0 * inv;
  out[n*3+1] = e1 * inv;
  out[n*3+2] = e2 * inv;
  float* outl = out + NROWS * 3;
  outl[n*3+0] = l0;
  outl[n*3+1] = l1;
  outl[n*3+2] = l2;
}

extern "C" void kernel_launch(void* const* d_in, const int* in_sizes, int n_in,
                              void* d_out, int out_size, void* d_ws, size_t ws_size,
                              hipStream_t stream) {
  const float* H     = (const float*)d_in[0];
  const float* Wc    = (const float*)d_in[1];
  const float* bc    = (const float*)d_in[2];
  const float* W1    = (const float*)d_in[3];
  const float* b1    = (const float*)d_in[4];
  const float* W2    = (const float*)d_in[5];
  const float* b2    = (const float*)d_in[6];
  const float* alpha = (const float*)d_in[7];
  float* out = (float*)d_out;

  char* ws = (char*)d_ws;
  u16*   F        = (u16*)ws;                               // 16 MiB
  float* CL       = (float*)(ws + 16777216);                // 96 KiB
  float* partials = (float*)(ws + 16777216 + 98304);        // 8192*144*4 = 4.5 MiB

  k_rowprep<<<NROWS, 256, 0, stream>>>(H, Wc, bc, F, CL);
  dim3 g2(64, NSPLIT);
  k_simtopk<<<g2, 256, 0, stream>>>(F, partials);
  k_finalize<<<NROWS / 256, 256, 0, stream>>>(partials, CL, W1, b1, W2, b2, alpha, out);
}

// Round 7
// 400.330 us; speedup vs baseline: 1.1114x; 1.1114x over previous
//
#include <hip/hip_runtime.h>
#include <hip/hip_bf16.h>

typedef __attribute__((ext_vector_type(4))) float f32x4;
typedef __attribute__((ext_vector_type(8))) short short8;
typedef unsigned short u16;

#define NROWS 8192
#define DM 1024
#define EPSF 1e-8f
#define NSPLIT 16     // column splits
#define SPLITW 512    // cols per split
#define NCT 4         // 128-col tiles per split

// async global->LDS, 16B per lane, wave-uniform LDS base (rule #21: linear dest,
// inverse-swizzled SOURCE, swizzle applied again on the ds_read side)
#define GLDS(gsrc, ldst) __builtin_amdgcn_global_load_lds(                 \
    (const __attribute__((address_space(1))) void*)(gsrc),                 \
    (__attribute__((address_space(3))) void*)(ldst), 16, 0, 0)

static __device__ __forceinline__ u16 f2bf(float x) {
  unsigned u = __float_as_uint(x);
  u += 0x7fffu + ((u >> 16) & 1u);   // RNE
  return (u16)(u >> 16);
}

// insert v into descending-sorted S[9]; all indices compile-time (stays in VGPRs)
static __device__ __forceinline__ void topk9_insert(float (&S)[9], float v) {
  if (v <= S[8]) return;
  S[8] = v;
#pragma unroll
  for (int q = 8; q > 0; --q) {
    float a = S[q - 1], b = S[q];
    S[q - 1] = fmaxf(a, b);
    S[q]     = fminf(a, b);
  }
}

// scan this thread's 16-col strip of one spilled half-tile; S statically bound
static __device__ __forceinline__ void scan_strip(
    float (&S)[9], const float* __restrict__ Cs, int srow, int cbase) {
  const float* crow = Cs + srow * 128;
#pragma unroll
  for (int g = 0; g < 4; ++g) {
    const int c0   = cbase + 4 * g;
    const int slot = ((c0 >> 2) + srow) & 31;          // additive rotate, ~2 lanes/slot
    const f32x4 v  = *(const f32x4*)(crow + (slot << 2));
    const float m  = fmaxf(fmaxf(v.x, v.y), fmaxf(v.z, v.w));
    if (m > S[8]) {
      topk9_insert(S, v.x); topk9_insert(S, v.y);
      topk9_insert(S, v.z); topk9_insert(S, v.w);
    }
  }
}

// ---------------- kernel 1: row norm -> bf16 F, content logits ----------------
__global__ __launch_bounds__(256) void k_rowprep(
    const float* __restrict__ H, const float* __restrict__ Wc,
    const float* __restrict__ bc, u16* __restrict__ F, float* __restrict__ CL)
{
  const int r = blockIdx.x;
  const int t = threadIdx.x;
  const int lane = t & 63;
  const int w = t >> 6;

  const float4 h  = ((const float4*)(H  + (size_t)r * DM))[t];
  const float4 c0 = ((const float4*)(Wc + 0 * DM))[t];
  const float4 c1 = ((const float4*)(Wc + 1 * DM))[t];
  const float4 c2 = ((const float4*)(Wc + 2 * DM))[t];

  float ss = h.x*h.x + h.y*h.y + h.z*h.z + h.w*h.w;
  float d0 = h.x*c0.x + h.y*c0.y + h.z*c0.z + h.w*c0.w;
  float d1 = h.x*c1.x + h.y*c1.y + h.z*c1.z + h.w*c1.w;
  float d2 = h.x*c2.x + h.y*c2.y + h.z*c2.z + h.w*c2.w;

#pragma unroll
  for (int off = 32; off > 0; off >>= 1) {
    ss += __shfl_down(ss, off);
    d0 += __shfl_down(d0, off);
    d1 += __shfl_down(d1, off);
    d2 += __shfl_down(d2, off);
  }
  __shared__ float red[4][4];
  __shared__ float bcast;
  if (lane == 0) { red[w][0] = ss; red[w][1] = d0; red[w][2] = d1; red[w][3] = d2; }
  __syncthreads();
  if (t == 0) {
    float S  = red[0][0] + red[1][0] + red[2][0] + red[3][0];
    float D0 = red[0][1] + red[1][1] + red[2][1] + red[3][1];
    float D1 = red[0][2] + red[1][2] + red[2][2] + red[3][2];
    float D2 = red[0][3] + red[1][3] + red[2][3] + red[3][3];
    bcast = 1.0f / (sqrtf(S) + EPSF);
    CL[r*3+0] = D0 + bc[0];
    CL[r*3+1] = D1 + bc[1];
    CL[r*3+2] = D2 + bc[2];
  }
  __syncthreads();
  const float invn = bcast;
  ushort4 o;
  o.x = f2bf(h.x * invn); o.y = f2bf(h.y * invn);
  o.z = f2bf(h.z * invn); o.w = f2bf(h.w * invn);
  ((ushort4*)(F + (size_t)r * DM))[t] = o;
}

// ---------------- kernel 2: sim GEMM (bf16 MFMA) fused with top-9 ----------------
// grid (64 rowblocks of 128, 16 colsplits of 512). 512 threads = 8 waves (2x4 grid):
// wave owns 64x32 -> acc = 4x2 frags = 32 AGPR; unified demand ~115 -> 4 waves/SIMD
// (16 waves/CU, 2 blocks). Scan: 8 threads/row x 16 cols, sA/sB statically bound.
__global__ __launch_bounds__(512, 4) void k_simtopk(
    const u16* __restrict__ F, float* __restrict__ partials)
{
  __shared__ char smem[37376];
  u16*   As = (u16*)smem;                  // [128][64] bf16 (swizzled chunks), 16 KiB
  u16*   Bs = (u16*)(smem + 16384);        // [128][64] bf16, 16 KiB
  float* Cs = (float*)smem;                // [64][128] f32 spill, rotate slots (32 KiB)
  float* Ms = (float*)smem;                // [128][73] merge buffer (37376 B)

  const int t    = threadIdx.x;
  const int lane = t & 63;
  const int w    = t >> 6;                 // 0..7
  const int wr   = (w >> 2) * 64;
  const int wc   = (w & 3) * 32;
  const int R0    = blockIdx.x * 128;
  const int CBASE = blockIdx.y * SPLITW;
  const int wbase16 = (t & ~63) * 16;      // wave-uniform LDS byte base

  float sA[9], sB[9];
#pragma unroll
  for (int q = 0; q < 9; ++q) { sA[q] = -1e30f; sB[q] = -1e30f; }

  const int srow  = t >> 3;                // scan row within half, 0..63
  const int cbase = (t & 7) * 16;          // 16-col strip

  for (int ct = 0; ct < NCT; ++ct) {
    const int C0 = CBASE + ct * 128;
    f32x4 acc[4][2];
#pragma unroll
    for (int i = 0; i < 4; ++i)
#pragma unroll
      for (int j = 0; j < 2; ++j)
        acc[i][j] = {0.f, 0.f, 0.f, 0.f};

    const char* Abase = (const char*)(F + (size_t)R0 * DM);
    const char* Bbase = (const char*)(F + (size_t)C0 * DM);
    for (int kk = 0; kk < 16; ++kk) {
      const int k0b = kk * 128;            // byte offset of k-chunk
#pragma unroll
      for (int it = 0; it < 2; ++it) {
        const int p  = it * 512 + t;       // chunk id 0..1023 (rematerializable)
        const int so = (p >> 3) * (DM * 2) + (((p & 7) ^ ((p >> 3) & 7)) * 16);
        GLDS(Abase + k0b + so, smem + it * 8192 + wbase16);
        GLDS(Bbase + k0b + so, smem + 16384 + it * 8192 + wbase16);
      }
      __syncthreads();   // compiler drains vmcnt(0) here
#pragma unroll
      for (int ks = 0; ks < 2; ++ks) {
        const int co = (((ks * 4 + (lane >> 4)) ^ (lane & 7))) * 8;  // i/j-invariant
        short8 b[2];
#pragma unroll
        for (int j = 0; j < 2; ++j)
          b[j] = *(const short8*)(Bs + (wc + j * 16 + (lane & 15)) * 64 + co);
#pragma unroll
        for (int i = 0; i < 4; ++i) {
          const short8 a = *(const short8*)(As + (wr + i * 16 + (lane & 15)) * 64 + co);
#pragma unroll
          for (int j = 0; j < 2; ++j)
            acc[i][j] = __builtin_amdgcn_mfma_f32_16x16x32_bf16(a, b[j], acc[i][j], 0, 0, 0);
        }
      }
      __syncthreads();
    }

    // spill + scan, one 64-row half at a time (C/D layout: col=lane&15, row=(lane>>4)*4+reg)
    // phys slot = ((col>>2) + row) & 31 : spill <=2-way, scan ~2-way (free)
    if ((w >> 2) == 0) {
#pragma unroll
      for (int i = 0; i < 4; ++i)
#pragma unroll
        for (int j = 0; j < 2; ++j)
#pragma unroll
          for (int q = 0; q < 4; ++q) {
            const int rr = i * 16 + (lane >> 4) * 4 + q;
            const int cc = wc + j * 16 + (lane & 15);
            const int slot = ((cc >> 2) + rr) & 31;
            Cs[rr * 128 + (slot << 2) + (cc & 3)] = acc[i][j][q];
          }
    }
    __syncthreads();
    scan_strip(sA, Cs, srow, cbase);
    __syncthreads();
    if ((w >> 2) == 1) {
#pragma unroll
      for (int i = 0; i < 4; ++i)
#pragma unroll
        for (int j = 0; j < 2; ++j)
#pragma unroll
          for (int q = 0; q < 4; ++q) {
            const int rr = i * 16 + (lane >> 4) * 4 + q;
            const int cc = wc + j * 16 + (lane & 15);
            const int slot = ((cc >> 2) + rr) & 31;
            Cs[rr * 128 + (slot << 2) + (cc & 3)] = acc[i][j][q];
          }
    }
    __syncthreads();
    scan_strip(sB, Cs, srow, cbase);
    __syncthreads();
  }

  // 8 lists per row -> merge -> top-9 partial for this colsplit
#pragma unroll
  for (int q = 0; q < 9; ++q) {
    Ms[srow        * 73 + (t & 7) * 9 + q] = sA[q];
    Ms[(64 + srow) * 73 + (t & 7) * 9 + q] = sB[q];
  }
  __syncthreads();
  if (t < 128) {
    const float* row = Ms + t * 73;
    float T[9];
#pragma unroll
    for (int q = 0; q < 9; ++q) T[q] = row[q];          // list 0, already descending
#pragma unroll
    for (int grp = 1; grp < 8; ++grp) {
      for (int gq = 0; gq < 9; ++gq) {
        const float v = row[grp * 9 + gq];
        if (v <= T[8]) break;                           // lists descending
        topk9_insert(T, v);
      }
    }
    float* dst = partials + (size_t)(R0 + t) * (NSPLIT * 9) + blockIdx.y * 9;
#pragma unroll
    for (int q = 0; q < 9; ++q) dst[q] = T[q];          // descending
  }
}

// ---------------- kernel 3: merge partials, features, MLP, mix, softmax ----------------
__global__ __launch_bounds__(256) void k_finalize(
    const float* __restrict__ partials, const float* __restrict__ CL,
    const float* __restrict__ W1, const float* __restrict__ b1,
    const float* __restrict__ W2, const float* __restrict__ b2,
    const float* __restrict__ alpha, float* __restrict__ out)
{
  const int n = blockIdx.x * 256 + threadIdx.x;
  if (n >= NROWS) return;
  const float* p = partials + (size_t)n * (NSPLIT * 9);
  float S[9];
#pragma unroll
  for (int q = 0; q < 9; ++q) S[q] = -1e30f;
  for (int grp = 0; grp < NSPLIT; ++grp) {
    for (int gq = 0; gq < 9; ++gq) {
      const float v = p[grp * 9 + gq];
      if (v <= S[8]) break;               // groups are descending
      topk9_insert(S, v);
    }
  }
  // S[0] is the self-similarity (max) -> dropped; knn sims are S[1..8]
  float sum = 0.f, sumsq = 0.f;
#pragma unroll
  for (int q = 1; q < 9; ++q) { sum += S[q]; sumsq += S[q] * S[q]; }
  const float mean_s  = sum * 0.125f;
  float var = (sumsq - 8.f * mean_s * mean_s) * (1.f / 7.f);  // ddof=1
  var = fmaxf(var, 0.f);
  const float tree    = sqrtf(var);
  const float density = 1.f - mean_s;
  const float outlier = (1.f - S[8]) / (density + EPSF);      // min sim = max dist

  float a0 = b2[0], a1 = b2[1], a2 = b2[2];
#pragma unroll
  for (int j = 0; j < 32; ++j) {
    float hj = W1[j*3+0]*tree + W1[j*3+1]*density + W1[j*3+2]*outlier + b1[j];
    hj = fmaxf(hj, 0.f);
    a0 += W2[j]      * hj;
    a1 += W2[32 + j] * hj;
    a2 += W2[64 + j] * hj;
  }
  const float mix = 1.f / (1.f + expf(-alpha[0]));
  const float im  = 1.f - mix;
  const float l0 = mix * CL[n*3+0] + im * a0;
  const float l1 = mix * CL[n*3+1] + im * a1;
  const float l2 = mix * CL[n*3+2] + im * a2;
  const float mx = fmaxf(l0, fmaxf(l1, l2));
  const float e0 = expf(l0 - mx), e1 = expf(l1 - mx), e2 = expf(l2 - mx);
  const float inv = 1.f / (e0 + e1 + e2);
  out[n*3+0] = e0 * inv;
  out[n*3+1] = e1 * inv;
  out[n*3+2] = e2 * inv;
  float* outl = out + NROWS * 3;
  outl[n*3+0] = l0;
  outl[n*3+1] = l1;
  outl[n*3+2] = l2;
}

extern "C" void kernel_launch(void* const* d_in, const int* in_sizes, int n_in,
                              void* d_out, int out_size, void* d_ws, size_t ws_size,
                              hipStream_t stream) {
  const float* H     = (const float*)d_in[0];
  const float* Wc    = (const float*)d_in[1];
  const float* bc    = (const float*)d_in[2];
  const float* W1    = (const float*)d_in[3];
  const float* b1    = (const float*)d_in[4];
  const float* W2    = (const float*)d_in[5];
  const float* b2    = (const float*)d_in[6];
  const float* alpha = (const float*)d_in[7];
  float* out = (float*)d_out;

  char* ws = (char*)d_ws;
  u16*   F        = (u16*)ws;                               // 16 MiB
  float* CL       = (float*)(ws + 16777216);                // 96 KiB
  float* partials = (float*)(ws + 16777216 + 98304);        // 8192*144*4 = 4.5 MiB

  k_rowprep<<<NROWS, 256, 0, stream>>>(H, Wc, bc, F, CL);
  dim3 g2(64, NSPLIT);
  k_simtopk<<<g2, 512, 0, stream>>>(F, partials);
  k_finalize<<<NROWS / 256, 256, 0, stream>>>(partials, CL, W1, b1, W2, b2, alpha, out);
}

// Round 8
// 218.569 us; speedup vs baseline: 2.0357x; 1.8316x over previous
//
#include <hip/hip_runtime.h>
#include <hip/hip_bf16.h>

typedef __attribute__((ext_vector_type(4))) float f32x4;
typedef __attribute__((ext_vector_type(8))) short short8;
typedef unsigned short u16;

#define NROWS 8192
#define DM 1024
#define EPSF 1e-8f
#define NSPLIT 16     // column splits
#define SPLITW 512    // cols per split
#define NCT 4         // 128-col tiles per split

// async global->LDS, 16B per lane, wave-uniform LDS base (rule #21: linear dest,
// inverse-swizzled SOURCE, swizzle applied again on the ds_read side)
#define GLDS(gsrc, ldst) __builtin_amdgcn_global_load_lds(                 \
    (const __attribute__((address_space(1))) void*)(gsrc),                 \
    (__attribute__((address_space(3))) void*)(ldst), 16, 0, 0)

static __device__ __forceinline__ u16 f2bf(float x) {
  unsigned u = __float_as_uint(x);
  u += 0x7fffu + ((u >> 16) & 1u);   // RNE
  return (u16)(u >> 16);
}

// insert v into descending-sorted S[9]; all indices compile-time (stays in VGPRs)
static __device__ __forceinline__ void topk9_insert(float (&S)[9], float v) {
  if (v <= S[8]) return;
  S[8] = v;
#pragma unroll
  for (int q = 8; q > 0; --q) {
    float a = S[q - 1], b = S[q];
    S[q - 1] = fmaxf(a, b);
    S[q]     = fminf(a, b);
  }
}

// scan one 64x128 spilled half-tile; S bound statically at each call site
static __device__ __forceinline__ void scan_half(
    float (&S)[9], const float* __restrict__ Cs, int srow, int scol) {
  const float* crow = Cs + srow * 128;
#pragma unroll
  for (int g = 0; g < 8; ++g) {
    const int c0   = scol + 4 * g;
    const int slot = ((c0 >> 2) + srow) & 31;          // additive rotate, 2 lanes/slot
    const f32x4 v  = *(const f32x4*)(crow + (slot << 2));
    const float m  = fmaxf(fmaxf(v.x, v.y), fmaxf(v.z, v.w));
    if (m > S[8]) {
      topk9_insert(S, v.x); topk9_insert(S, v.y);
      topk9_insert(S, v.z); topk9_insert(S, v.w);
    }
  }
}

// issue one K-step's async staging (A+B tiles) into the given LDS buffers
static __device__ __forceinline__ void stage_tile(
    const char* __restrict__ Abase, const char* __restrict__ Bbase,
    int k0b, char* smem, int aoff, int boff, int t, int wchunk)
{
#pragma unroll
  for (int it = 0; it < 4; ++it) {
    const int p  = it * 256 + t;           // chunk id 0..1023 (rematerializable)
    const int so = (p >> 3) * (DM * 2) + (((p & 7) ^ ((p >> 3) & 7)) * 16);
    GLDS(Abase + k0b + so, smem + aoff + (it * 256 + wchunk) * 16);
    GLDS(Bbase + k0b + so, smem + boff + (it * 256 + wchunk) * 16);
  }
}

// one K-step of MFMA from staged LDS buffers
static __device__ __forceinline__ void compute_tile(
    f32x4 (&acc)[4][4], const u16* __restrict__ As, const u16* __restrict__ Bs,
    int lane, int wr, int wc)
{
#pragma unroll
  for (int ks = 0; ks < 2; ++ks) {
    const int co = ((ks * 4 + (lane >> 4)) ^ (lane & 7)) * 8;   // i/j-invariant
    short8 b[4];
#pragma unroll
    for (int j = 0; j < 4; ++j)
      b[j] = *(const short8*)(Bs + (wc + j * 16 + (lane & 15)) * 64 + co);
#pragma unroll
    for (int i = 0; i < 4; ++i) {
      const short8 a = *(const short8*)(As + (wr + i * 16 + (lane & 15)) * 64 + co);
#pragma unroll
      for (int j = 0; j < 4; ++j)
        acc[i][j] = __builtin_amdgcn_mfma_f32_16x16x32_bf16(a, b[j], acc[i][j], 0, 0, 0);
    }
  }
}

// ---------------- kernel 1: row norm -> bf16 F, content logits ----------------
__global__ __launch_bounds__(256) void k_rowprep(
    const float* __restrict__ H, const float* __restrict__ Wc,
    const float* __restrict__ bc, u16* __restrict__ F, float* __restrict__ CL)
{
  const int r = blockIdx.x;
  const int t = threadIdx.x;
  const int lane = t & 63;
  const int w = t >> 6;

  const float4 h  = ((const float4*)(H  + (size_t)r * DM))[t];
  const float4 c0 = ((const float4*)(Wc + 0 * DM))[t];
  const float4 c1 = ((const float4*)(Wc + 1 * DM))[t];
  const float4 c2 = ((const float4*)(Wc + 2 * DM))[t];

  float ss = h.x*h.x + h.y*h.y + h.z*h.z + h.w*h.w;
  float d0 = h.x*c0.x + h.y*c0.y + h.z*c0.z + h.w*c0.w;
  float d1 = h.x*c1.x + h.y*c1.y + h.z*c1.z + h.w*c1.w;
  float d2 = h.x*c2.x + h.y*c2.y + h.z*c2.z + h.w*c2.w;

#pragma unroll
  for (int off = 32; off > 0; off >>= 1) {
    ss += __shfl_down(ss, off);
    d0 += __shfl_down(d0, off);
    d1 += __shfl_down(d1, off);
    d2 += __shfl_down(d2, off);
  }
  __shared__ float red[4][4];
  __shared__ float bcast;
  if (lane == 0) { red[w][0] = ss; red[w][1] = d0; red[w][2] = d1; red[w][3] = d2; }
  __syncthreads();
  if (t == 0) {
    float S  = red[0][0] + red[1][0] + red[2][0] + red[3][0];
    float D0 = red[0][1] + red[1][1] + red[2][1] + red[3][1];
    float D1 = red[0][2] + red[1][2] + red[2][2] + red[3][2];
    float D2 = red[0][3] + red[1][3] + red[2][3] + red[3][3];
    bcast = 1.0f / (sqrtf(S) + EPSF);
    CL[r*3+0] = D0 + bc[0];
    CL[r*3+1] = D1 + bc[1];
    CL[r*3+2] = D2 + bc[2];
  }
  __syncthreads();
  const float invn = bcast;
  ushort4 o;
  o.x = f2bf(h.x * invn); o.y = f2bf(h.y * invn);
  o.z = f2bf(h.z * invn); o.w = f2bf(h.w * invn);
  ((ushort4*)(F + (size_t)r * DM))[t] = o;
}

// ---------------- kernel 2: sim GEMM (bf16 MFMA) fused with top-9 ----------------
// grid (64 rowblocks of 128, 16 colsplits of 512). 256 threads = 4 waves.
// 2-phase double-buffered staging (T3 minimum recipe): STAGE(next) issued BEFORE
// compute(cur); ONE barrier per K-step; the barrier's implicit vmcnt(0) then waits
// on loads covered by the whole compute phase. No launch-bound squeeze (R3/R5/R6
// all scratch-spilled): spill-free codegen at 2 blocks/CU beats spilled 3-4.
__global__ __launch_bounds__(256, 2) void k_simtopk(
    const u16* __restrict__ F, float* __restrict__ partials)
{
  __shared__ char smem[65536];
  u16*   A0s = (u16*)smem;                 // [128][64] bf16 swizzled, 16 KiB
  u16*   B0s = (u16*)(smem + 16384);
  u16*   A1s = (u16*)(smem + 32768);
  u16*   B1s = (u16*)(smem + 49152);
  float* Cs  = (float*)smem;               // [64][128] f32 spill overlay (32 KiB, on A0/B0)
  float* Ms  = (float*)smem;               // [128][18] merge overlay (9 KiB)

  const int t    = threadIdx.x;
  const int lane = t & 63;
  const int w    = t >> 6;
  const int wr   = (w >> 1) * 64;
  const int wc   = (w & 1) * 64;
  const int R0    = blockIdx.x * 128;
  const int CBASE = blockIdx.y * SPLITW;
  const int wchunk = t & 192;              // wave-uniform chunk base within 256

  float sA[9], sB[9];
#pragma unroll
  for (int q = 0; q < 9; ++q) { sA[q] = -1e30f; sB[q] = -1e30f; }

  const int srow = t & 63;   // scan row within 64-row half
  const int scol = w * 32;   // scan col base (wave = col quarter)

  for (int ct = 0; ct < NCT; ++ct) {
    const int C0 = CBASE + ct * 128;
    f32x4 acc[4][4];
#pragma unroll
    for (int i = 0; i < 4; ++i)
#pragma unroll
      for (int j = 0; j < 4; ++j)
        acc[i][j] = {0.f, 0.f, 0.f, 0.f};

    const char* Abase = (const char*)(F + (size_t)R0 * DM);
    const char* Bbase = (const char*)(F + (size_t)C0 * DM);

    // prologue: fill buf0 with kk=0
    stage_tile(Abase, Bbase, 0, smem, 0, 16384, t, wchunk);
    __syncthreads();                       // drains vmcnt(0): buf0 ready

    for (int kkp = 0; kkp < 8; ++kkp) {
      const int kb = kkp * 256;            // byte offset of even k-chunk
      // phase A: prefetch odd-k into buf1, compute even-k from buf0
      stage_tile(Abase, Bbase, kb + 128, smem, 32768, 49152, t, wchunk);
      compute_tile(acc, A0s, B0s, lane, wr, wc);
      __syncthreads();                     // buf1 ready; all reads of buf0 done
      // phase B: prefetch next-even-k into buf0, compute odd-k from buf1
      if (kkp < 7)
        stage_tile(Abase, Bbase, kb + 256, smem, 0, 16384, t, wchunk);
      compute_tile(acc, A1s, B1s, lane, wr, wc);
      __syncthreads();                     // buf0 ready; all reads of buf1 done
    }

    // spill + scan, one 64-row half at a time (C/D layout: col=lane&15, row=(lane>>4)*4+reg)
    // phys slot = ((col>>2) + row) & 31 : spill <=2-way, scan exactly 2-way (free)
    if ((w >> 1) == 0) {
#pragma unroll
      for (int i = 0; i < 4; ++i)
#pragma unroll
        for (int j = 0; j < 4; ++j)
#pragma unroll
          for (int q = 0; q < 4; ++q) {
            const int rr = i * 16 + (lane >> 4) * 4 + q;
            const int cc = wc + j * 16 + (lane & 15);
            const int slot = ((cc >> 2) + rr) & 31;
            Cs[rr * 128 + (slot << 2) + (cc & 3)] = acc[i][j][q];
          }
    }
    __syncthreads();
    scan_half(sA, Cs, srow, scol);
    __syncthreads();
    if ((w >> 1) == 1) {
#pragma unroll
      for (int i = 0; i < 4; ++i)
#pragma unroll
        for (int j = 0; j < 4; ++j)
#pragma unroll
          for (int q = 0; q < 4; ++q) {
            const int rr = i * 16 + (lane >> 4) * 4 + q;
            const int cc = wc + j * 16 + (lane & 15);
            const int slot = ((cc >> 2) + rr) & 31;
            Cs[rr * 128 + (slot << 2) + (cc & 3)] = acc[i][j][q];
          }
    }
    __syncthreads();
    scan_half(sB, Cs, srow, scol);
    __syncthreads();
  }

  // merge the 4 col-quarter lists per row -> top-9 partial for this colsplit
#pragma unroll
  for (int q = 0; q < 9; ++q) {
    Ms[(srow)      * 18 + 0] = Ms[(srow) * 18 + 0];  // no-op keeps layout explicit
  }
  // store: two halves x 4 waves -> [128][18] won't fit 4 lists; use [128][36] region
  {
    float* M4 = (float*)smem;              // [128][36] merge buffer (18 KiB overlay)
#pragma unroll
    for (int q = 0; q < 9; ++q) {
      M4[(srow)      * 36 + w * 9 + q] = sA[q];
      M4[(64 + srow) * 36 + w * 9 + q] = sB[q];
    }
    __syncthreads();
    if (t < 128) {
      const float* row = M4 + t * 36;
      float T[9];
#pragma unroll
      for (int q = 0; q < 9; ++q) T[q] = row[q];        // list 0, already descending
#pragma unroll
      for (int grp = 1; grp < 4; ++grp) {
        for (int gq = 0; gq < 9; ++gq) {
          const float v = row[grp * 9 + gq];
          if (v <= T[8]) break;                         // lists descending
          topk9_insert(T, v);
        }
      }
      float* dst = partials + (size_t)(R0 + t) * (NSPLIT * 9) + blockIdx.y * 9;
#pragma unroll
      for (int q = 0; q < 9; ++q) dst[q] = T[q];        // descending
    }
  }
}

// ---------------- kernel 3: merge partials, features, MLP, mix, softmax ----------------
__global__ __launch_bounds__(256) void k_finalize(
    const float* __restrict__ partials, const float* __restrict__ CL,
    const float* __restrict__ W1, const float* __restrict__ b1,
    const float* __restrict__ W2, const float* __restrict__ b2,
    const float* __restrict__ alpha, float* __restrict__ out)
{
  const int n = blockIdx.x * 256 + threadIdx.x;
  if (n >= NROWS) return;
  const float* p = partials + (size_t)n * (NSPLIT * 9);
  float S[9];
#pragma unroll
  for (int q = 0; q < 9; ++q) S[q] = -1e30f;
  for (int grp = 0; grp < NSPLIT; ++grp) {
    for (int gq = 0; gq < 9; ++gq) {
      const float v = p[grp * 9 + gq];
      if (v <= S[8]) break;               // groups are descending
      topk9_insert(S, v);
    }
  }
  // S[0] is the self-similarity (max) -> dropped; knn sims are S[1..8]
  float sum = 0.f, sumsq = 0.f;
#pragma unroll
  for (int q = 1; q < 9; ++q) { sum += S[q]; sumsq += S[q] * S[q]; }
  const float mean_s  = sum * 0.125f;
  float var = (sumsq - 8.f * mean_s * mean_s) * (1.f / 7.f);  // ddof=1
  var = fmaxf(var, 0.f);
  const float tree    = sqrtf(var);
  const float density = 1.f - mean_s;
  const float outlier = (1.f - S[8]) / (density + EPSF);      // min sim = max dist

  float a0 = b2[0], a1 = b2[1], a2 = b2[2];
#pragma unroll
  for (int j = 0; j < 32; ++j) {
    float hj = W1[j*3+0]*tree + W1[j*3+1]*density + W1[j*3+2]*outlier + b1[j];
    hj = fmaxf(hj, 0.f);
    a0 += W2[j]      * hj;
    a1 += W2[32 + j] * hj;
    a2 += W2[64 + j] * hj;
  }
  const float mix = 1.f / (1.f + expf(-alpha[0]));
  const float im  = 1.f - mix;
  const float l0 = mix * CL[n*3+0] + im * a0;
  const float l1 = mix * CL[n*3+1] + im * a1;
  const float l2 = mix * CL[n*3+2] + im * a2;
  const float mx = fmaxf(l0, fmaxf(l1, l2));
  const float e0 = expf(l0 - mx), e1 = expf(l1 - mx), e2 = expf(l2 - mx);
  const float inv = 1.f / (e0 + e1 + e2);
  out[n*3+0] = e0 * inv;
  out[n*3+1] = e1 * inv;
  out[n*3+2] = e2 * inv;
  float* outl = out + NROWS * 3;
  outl[n*3+0] = l0;
  outl[n*3+1] = l1;
  outl[n*3+2] = l2;
}

extern "C" void kernel_launch(void* const* d_in, const int* in_sizes, int n_in,
                              void* d_out, int out_size, void* d_ws, size_t ws_size,
                              hipStream_t stream) {
  const float* H     = (const float*)d_in[0];
  const float* Wc    = (const float*)d_in[1];
  const float* bc    = (const float*)d_in[2];
  const float* W1    = (const float*)d_in[3];
  const float* b1    = (const float*)d_in[4];
  const float* W2    = (const float*)d_in[5];
  const float* b2    = (const float*)d_in[6];
  const float* alpha = (const float*)d_in[7];
  float* out = (float*)d_out;

  char* ws = (char*)d_ws;
  u16*   F        = (u16*)ws;                               // 16 MiB
  float* CL       = (float*)(ws + 16777216);                // 96 KiB
  float* partials = (float*)(ws + 16777216 + 98304);        // 8192*144*4 = 4.5 MiB

  k_rowprep<<<NROWS, 256, 0, stream>>>(H, Wc, bc, F, CL);
  dim3 g2(64, NSPLIT);
  k_simtopk<<<g2, 256, 0, stream>>>(F, partials);
  k_finalize<<<NROWS / 256, 256, 0, stream>>>(partials, CL, W1, b1, W2, b2, alpha, out);
}